// Round 5
// baseline (5850.996 us; speedup 1.0000x reference)
//
#include <hip/hip_runtime.h>

typedef _Float16 half8 __attribute__((ext_vector_type(8)));
typedef _Float16 half4 __attribute__((ext_vector_type(4)));
typedef float f32x16 __attribute__((ext_vector_type(16)));
typedef unsigned long long u64;

#define SEQ 512
#define HID 1024
#define HB 65536  // elements per h slice / per x time-slice

// ---- LDS layout (bytes) ----
#define WROW 2064  // 2048 B data + 16 B pad -> conflict-free ds_read_b128
#define LDS_WIH 0        // 32 rows x 2064
#define LDS_WHH 66048    // 32 rows x 2064
#define LDS_GX0 132096   // [64][36] f32 (input-gate partials, ping)
#define LDS_GX1 141312   // [64][36] f32 (pong)
#define LDS_GH  150528   // [64][36] f32 (recurrent partials)
#define LDS_C   159744   // [512] f32 cell state
#define LDS_BIAS 161792  // [32] f32
#define LDS_ARR 161920   // arrive counter
#define LDS_TOTAL 161984

__device__ __forceinline__ float sigf(float x) { return 1.0f / (1.0f + __expf(-x)); }
__device__ __forceinline__ float tanhfast(float x) {
  x = fminf(fmaxf(x, -44.0f), 44.0f);
  float e = __expf(2.0f * x);
  return (e - 1.0f) / (e + 1.0f);
}

__global__ __launch_bounds__(256, 1) void cvt_f32_f16(const float* __restrict__ in,
                                                      _Float16* __restrict__ out, int n4) {
  int stride = gridDim.x * blockDim.x;
  for (int i = blockIdx.x * blockDim.x + threadIdx.x; i < n4; i += stride) {
    float4 v = ((const float4*)in)[i];
    half4 o;
    o[0] = (_Float16)v.x; o[1] = (_Float16)v.y; o[2] = (_Float16)v.z; o[3] = (_Float16)v.w;
    ((half4*)out)[i] = o;
  }
}

// Poll 128 u32 flags (64 u64 words, one per lane) until min >= tgt.
__device__ __forceinline__ void pollFlags(const unsigned* f, unsigned tgt, int lane) {
  const u64* fp = (const u64*)f;
  for (;;) {
    u64 v = __hip_atomic_load(fp + lane, __ATOMIC_RELAXED, __HIP_MEMORY_SCOPE_AGENT);
    unsigned a = (unsigned)v, b = (unsigned)(v >> 32);
    unsigned mn = a < b ? a : b;
    if (__all(mn >= tgt)) break;
    __builtin_amdgcn_s_sleep(1);
  }
}

// One wave's [32 batch] x [32 gate] x K=1024 GEMM. A: plain cached loads
// (write-once h history -> L2-amplified broadcast). B: LDS fp16 rows, stride
// 2064 B (conflict-free b128). 8 windows x 8 ksteps; A prefetched 3 windows.
__device__ __forceinline__ f32x16 gemm_k(const _Float16* aPtr, const char* wB, int bsub) {
  f32x16 acc[4];
#pragma unroll
  for (int q = 0; q < 4; ++q)
#pragma unroll
    for (int i = 0; i < 16; ++i) acc[q][i] = 0.0f;

  half8 aw[4][8];
  half8 bw[2][8];
#pragma unroll
  for (int w0 = 0; w0 < 3; ++w0)
#pragma unroll
    for (int u = 0; u < 8; ++u) aw[w0][u] = *(const half8*)(aPtr + (w0 * 8 + u) * 16);
#pragma unroll
  for (int u = 0; u < 8; ++u) bw[0][u] = *(const half8*)(wB + u * 32 + bsub);

#pragma unroll
  for (int w = 0; w < 8; ++w) {
    if (w + 3 < 8) {
#pragma unroll
      for (int u = 0; u < 8; ++u)
        aw[(w + 3) & 3][u] = *(const half8*)(aPtr + ((w + 3) * 8 + u) * 16);
    }
    if (w + 1 < 8) {
#pragma unroll
      for (int u = 0; u < 8; ++u)
        bw[(w + 1) & 1][u] = *(const half8*)(wB + ((w + 1) * 8 + u) * 32 + bsub);
    }
#pragma unroll
    for (int u = 0; u < 8; ++u)
      acc[u & 3] = __builtin_amdgcn_mfma_f32_32x32x16_f16(aw[w & 3][u], bw[w & 1][u],
                                                          acc[u & 3], 0, 0, 0);
  }
  return acc[0] + acc[1] + acc[2] + acc[3];
}

__device__ __forceinline__ void writeGates(float* gbuf, const f32x16& t, int mtile, int lane) {
#pragma unroll
  for (int r = 0; r < 16; ++r) {
    int bl = (r & 3) + ((r >> 2) << 3) + ((lane >> 5) << 2);
    gbuf[(mtile * 32 + bl) * 36 + (lane & 31)] = t[r];
  }
}

// Persistent fused 2-layer LSTM. WGs 0..127 layer0, 128..255 layer1.
// Per WG: waves 0,1 (gsel0) = input-GEMM waves; waves 2,3 (gsel1) = recurrent.
// Iteration k (own step): gsel0 precomputes input gates for step k+1 (operand
// always available: xh / h0 history, layer1 polls flags0 >= k+2); gsel1 polls
// own-layer flags >= k then does the recurrent GEMM on hSelf[k]. Epilogue
// combines gX[k&1] + gH, stores h slice k+1 (sc1 WT), drains, publishes flag
// k+1, THEN issues y/out stores (off the release path).
__global__ __launch_bounds__(256, 1) void lstm_fused(
    const _Float16* __restrict__ xh,
    const float* __restrict__ Wih0, const float* __restrict__ Whh0, const float* __restrict__ b0,
    const float* __restrict__ Wih1, const float* __restrict__ Whh1, const float* __restrict__ b1,
    _Float16* __restrict__ h0buf, _Float16* __restrict__ h1buf,
    unsigned* __restrict__ flags, float* __restrict__ out) {
  extern __shared__ char smem[];
  float* gH = (float*)(smem + LDS_GH);
  float* cst = (float*)(smem + LDS_C);
  float* bls = (float*)(smem + LDS_BIAS);
  unsigned* arrCnt = (unsigned*)(smem + LDS_ARR);

  const int tid = threadIdx.x;
  const int lane = tid & 63;
  const int wave = tid >> 6;
  const int mtile = wave & 1;   // which 32 batches
  const int gsel = wave >> 1;   // 0 = input waves, 1 = recurrent waves
  const int wg = blockIdx.x;
  const int layer = wg >> 7;
  const int j0 = (wg & 127) * 8;

  // ---- prologue: stage W slices (fp32 global -> fp16 LDS) ----
  const float* wsrc0 = layer ? Wih1 : Wih0;
  const float* wsrc1 = layer ? Whh1 : Whh0;
  for (int m = 0; m < 2; ++m) {
    const float* src = m ? wsrc1 : wsrc0;
    char* base = smem + (m ? LDS_WHH : LDS_WIH);
    for (int q = tid; q < 4096; q += 256) {
      int r = q >> 7;               // local gate row 0..31
      int kc = (q & 127) << 3;      // k chunk base (elements)
      int grow = ((r >> 3) << 10) + j0 + (r & 7);  // global gate row
      const float* sp = src + (size_t)grow * 1024 + kc;
      half8 v;
#pragma unroll
      for (int j = 0; j < 8; ++j) v[j] = (_Float16)sp[j];
      *(half8*)(base + r * WROW + kc * 2) = v;
    }
  }
  const float* bsrc = layer ? b1 : b0;
  if (tid < 32) {
    int grow = ((tid >> 3) << 10) + j0 + (tid & 7);
    bls[tid] = bsrc[grow];
  }
  for (int q = tid; q < 512; q += 256) cst[q] = 0.0f;
  if (tid == 0) *arrCnt = 0u;
  __syncthreads();

  // per-wave constant addressing
  const int arow = mtile * 32 + (lane & 31);   // batch row for A fragment
  const int asub = (lane >> 5) << 3;           // k sub-offset (elements)
  const int brow = lane & 31;                  // gate row for B fragment
  const int bsub = (lane >> 5) << 4;           // k sub-offset (bytes)
  const char* wIH = smem + LDS_WIH + brow * WROW;
  const char* wHH = smem + LDS_WHH + brow * WROW;
  _Float16* hSelf = layer ? h1buf : h0buf;
  const unsigned* flagsSelf = flags + (layer << 7);
  float* outy = out;
  float* outh = out + 33554432;
  float* outc = out + 33685504;

  // prologue phase A(0): input gates for step 0 -> gX0
  if (gsel == 0) {
    if (layer) pollFlags(flags, 1u, lane);  // need h0 slice 1 (= y0[0])
    const _Float16* aB = layer ? (h0buf + (size_t)1 * HB) : xh;
    f32x16 t = gemm_k(aB + arow * HID + asub, wIH, bsub);
    writeGates((float*)(smem + LDS_GX0), t, mtile, lane);
  }

  for (int k = 0; k < SEQ; ++k) {
    __syncthreads();  // epilogue k-1 fully done before gH/gX overwrite
    if (gsel == 0) {
      if (k + 1 < SEQ) {  // phase A(k+1)
        if (layer) pollFlags(flags, (unsigned)(k + 2), lane);
        const _Float16* aB =
            layer ? (h0buf + (size_t)(k + 2) * HB) : (xh + (size_t)(k + 1) * HB);
        f32x16 t = gemm_k(aB + arow * HID + asub, wIH, bsub);
        writeGates((float*)(smem + ((k + 1) & 1 ? LDS_GX1 : LDS_GX0)), t, mtile, lane);
      }
    } else {
      if (k > 0) pollFlags(flagsSelf, (unsigned)k, lane);  // own h slice k ready
      f32x16 t = gemm_k(hSelf + (size_t)k * HB + arow * HID + asub, wHH, bsub);
      writeGates(gH, t, mtile, lane);
    }
    __syncthreads();  // gX[k&1] (from prev iter / prologue) + gH complete

    // ---- epilogue step k (all 256 threads, 2 items each) ----
    const float* gX = (const float*)(smem + ((k & 1) ? LDS_GX1 : LDS_GX0));
    u64* hw64 = (u64*)(hSelf + (size_t)(k + 1) * HB);
    const bool last = (k == SEQ - 1);
    float hnv[2], cnv[2];
#pragma unroll
    for (int it = 0; it < 2; ++it) {
      int item = tid + it * 256;
      int b = item >> 3, j = item & 7;
      float vi = gX[b * 36 + j] + gH[b * 36 + j] + bls[j];
      float vf = gX[b * 36 + 8 + j] + gH[b * 36 + 8 + j] + bls[8 + j];
      float vg = gX[b * 36 + 16 + j] + gH[b * 36 + 16 + j] + bls[16 + j];
      float vo = gX[b * 36 + 24 + j] + gH[b * 36 + 24 + j] + bls[24 + j];
      float i_ = sigf(vi), f_ = sigf(vf), g_ = tanhfast(vg), o_ = sigf(vo);
      float cp = cst[item];
      float hn = o_ * tanhfast(cp);  // faithful: h uses PREVIOUS cell state
      float cn = f_ * cp + i_ * g_;
      cst[item] = cn;
      hnv[it] = hn; cnv[it] = cn;
      int col = j0 + j;
      // pack 4 cols into u64, one WT store per 4 lanes
      union { _Float16 h; unsigned short u; } hb; hb.h = (_Float16)hn;
      unsigned lo = (unsigned)hb.u;
      unsigned pr1 = (unsigned)__shfl_xor((int)lo, 1, 64);
      unsigned pk32 = lo | (pr1 << 16);
      u64 pr2 = (u64)(unsigned)__shfl_xor((int)pk32, 2, 64);
      if ((j & 3) == 0) {
        u64 v = (u64)pk32 | (pr2 << 32);
        __hip_atomic_store(hw64 + b * 256 + (col >> 2), v, __ATOMIC_RELAXED,
                           __HIP_MEMORY_SCOPE_AGENT);
      }
    }
    // ---- release: per-wave drain + LDS arrive; last wave publishes flag ----
    asm volatile("s_waitcnt vmcnt(0)" ::: "memory");
    if (lane == 0) {
      unsigned old = atomicAdd(arrCnt, 1u);
      if (old == 4u * (unsigned)k + 3u)
        __hip_atomic_store(&flags[wg], (unsigned)(k + 1), __ATOMIC_RELAXED,
                           __HIP_MEMORY_SCOPE_AGENT);
    }
    // ---- y / final-state stores (off the release path) ----
#pragma unroll
    for (int it = 0; it < 2; ++it) {
      int item = tid + it * 256;
      int b = item >> 3, j = item & 7;
      int col = j0 + j;
      if (layer)
        __builtin_nontemporal_store(hnv[it], &outy[(size_t)k * HB + b * HID + col]);
      if (last) {
        __builtin_nontemporal_store(hnv[it], &outh[layer * HB + b * HID + col]);
        __builtin_nontemporal_store(cnv[it], &outc[layer * HB + b * HID + col]);
      }
    }
  }
}

extern "C" void kernel_launch(void* const* d_in, const int* in_sizes, int n_in,
                              void* d_out, int out_size, void* d_ws, size_t ws_size,
                              hipStream_t stream) {
  const float* x = (const float*)d_in[0];
  const float* Wih0 = (const float*)d_in[1];
  const float* Whh0 = (const float*)d_in[2];
  const float* b0 = (const float*)d_in[3];
  const float* Wih1 = (const float*)d_in[4];
  const float* Whh1 = (const float*)d_in[5];
  const float* b1 = (const float*)d_in[6];
  float* out = (float*)d_out;

  char* ws = (char*)d_ws;
  _Float16* xh = (_Float16*)ws;                    // 512*64*1024 f16 = 67,108,864 B
  _Float16* h0 = (_Float16*)(ws + 67108864);       // 513 slices x 131072 B
  _Float16* h1 = (_Float16*)(ws + 134348800);      // 513 slices x 131072 B
  unsigned* flags = (unsigned*)(ws + 201588736);   // 256 u32 (layer0: 0..127, layer1: 128..255)

  hipMemsetAsync(h0, 0, 131072, stream);
  hipMemsetAsync(h1, 0, 131072, stream);
  hipMemsetAsync(flags, 0, 1024, stream);
  cvt_f32_f16<<<2048, 256, 0, stream>>>(x, xh, 33554432 / 4);
  lstm_fused<<<256, 256, LDS_TOTAL, stream>>>(xh, Wih0, Whh0, b0, Wih1, Whh1, b1,
                                              h0, h1, flags, out);
}